// Round 1
// baseline (2594.774 us; speedup 1.0000x reference)
//
#include <hip/hip_runtime.h>
#include <hip/hip_bf16.h>
#include <stdint.h>

// Problem constants (S=8, B=16, N=500, D=128, K=50, L=6)
#define G_   128
#define N_   500
#define D_   128
#define K_   50
#define L_   6
#define NW_  16            // adjacency words per row (512 bits >= 500)
#define ROWT 125           // row tiles per graph (4 rows/block)

#define ADJ_BYTES ((size_t)G_ * N_ * NW_ * 4)          // 4,096,000
#define H_BYTES   ((size_t)G_ * N_ * D_ * 4)           // 32,768,000

__device__ __forceinline__ float silu_f(float z) {
    return z / (1.0f + expf(-z));
}

// ---------------------------------------------------------------------------
// K0: kNN selection + symmetric bitmask adjacency.
// One wave per node-row; coords in LDS; 50x min-extract with shuffle reduce.
// ---------------------------------------------------------------------------
__global__ __launch_bounds__(256) void knn_kernel(const float* __restrict__ x,
                                                  uint32_t* __restrict__ adj) {
    int g    = blockIdx.x / ROWT;
    int tile = blockIdx.x % ROWT;
    int wave = threadIdx.x >> 6;
    int lane = threadIdx.x & 63;
    int i    = tile * 4 + wave;   // 0..499

    __shared__ float2 c[N_];
    for (int t = threadIdx.x; t < N_; t += 256)
        c[t] = ((const float2*)x)[(size_t)g * N_ + t];
    __syncthreads();

    float2 ci = c[i];
    float d[8];
#pragma unroll
    for (int r = 0; r < 8; ++r) {
        int j = lane + r * 64;
        if (j < N_ && j != i) {
            float dx = ci.x - c[j].x, dy = ci.y - c[j].y;
            d[r] = sqrtf(dx * dx + dy * dy + 1e-12f);
        } else {
            d[r] = 3.0e38f;
        }
    }

    unsigned used = 0;
    uint32_t myword = 0;
    size_t rowbase = (size_t)g * N_;

    for (int k = 0; k < K_; ++k) {
        float v = 3.0e38f;
        int jm = 0x7fffffff;
#pragma unroll
        for (int r = 0; r < 8; ++r) {
            if (!(used & (1u << r)) && d[r] < v) { v = d[r]; jm = lane + r * 64; }
        }
#pragma unroll
        for (int off = 32; off > 0; off >>= 1) {
            float ov = __shfl_xor(v, off);
            int   oj = __shfl_xor(jm, off);
            if (ov < v || (ov == v && oj < jm)) { v = ov; jm = oj; }
        }
        // winner lane retires its slot
        if ((jm & 63) == lane) used |= 1u << (jm >> 6);
        // accumulate bit j into this row's local mask (lane w owns word w)
        if ((jm >> 5) == lane) myword |= 1u << (jm & 31);
        // symmetric edge: row jm gets bit i
        if (lane == 0)
            atomicOr(&adj[(rowbase + (size_t)jm) * NW_ + (i >> 5)], 1u << (i & 31));
    }
    if (lane < NW_)
        atomicOr(&adj[(rowbase + (size_t)i) * NW_ + lane], myword);
}

// ---------------------------------------------------------------------------
// K1: h0 = silu(coords @ Wn + bn)
// ---------------------------------------------------------------------------
__global__ __launch_bounds__(256) void enc_kernel(const float* __restrict__ x,
                                                  const float* __restrict__ Wn,
                                                  const float* __restrict__ bn,
                                                  float* __restrict__ h) {
    int idx = blockIdx.x * 256 + threadIdx.x;   // < G*N*D = 8,192,000
    int dd  = idx & (D_ - 1);
    int row = idx >> 7;
    float x0 = x[(size_t)row * 2];
    float x1 = x[(size_t)row * 2 + 1];
    float z = x0 * Wn[dd] + x1 * Wn[D_ + dd] + bn[dd];
    h[idx] = silu_f(z);
}

// ---------------------------------------------------------------------------
// K2: sparse aggregation  m[i,:] = sum_j silu(we*dist(i,j)+be) * h[j,:]
// One wave per row; lane owns a float2 slice of D=128.
// ---------------------------------------------------------------------------
__global__ __launch_bounds__(256) void agg_kernel(const float* __restrict__ x,
                                                  const uint32_t* __restrict__ adj,
                                                  const float* __restrict__ h,
                                                  float* __restrict__ m,
                                                  const float* __restrict__ we,
                                                  const float* __restrict__ be,
                                                  int l) {
    int g    = blockIdx.x / ROWT;
    int tile = blockIdx.x % ROWT;
    int wave = threadIdx.x >> 6;
    int lane = threadIdx.x & 63;
    int i    = tile * 4 + wave;

    __shared__ float2 c[N_];
    for (int t = threadIdx.x; t < N_; t += 256)
        c[t] = ((const float2*)x)[(size_t)g * N_ + t];
    __syncthreads();

    float wel = we[l], bel = be[l];
    float2 ci = c[i];
    const uint32_t* arow = adj + ((size_t)g * N_ + i) * NW_;
    const float2* hg = (const float2*)(h + (size_t)g * N_ * D_);

    float ax = 0.0f, ay = 0.0f;
    for (int w = 0; w < NW_; ++w) {
        uint32_t mask = arow[w];
        int jbase = w * 32;
        while (mask) {
            int b = __ffs(mask) - 1;
            mask &= mask - 1;
            int j = jbase + b;
            float dx = ci.x - c[j].x, dy = ci.y - c[j].y;
            float dist = sqrtf(dx * dx + dy * dy + 1e-12f);
            float z = wel * dist + bel;
            float wgt = z / (1.0f + expf(-z));
            float2 hj = hg[(size_t)j * 64 + lane];
            ax += wgt * hj.x;
            ay += wgt * hj.y;
        }
    }
    float2* mrow = (float2*)(m + ((size_t)g * N_ + i) * D_);
    mrow[lane] = make_float2(ax, ay);
}

// ---------------------------------------------------------------------------
// K3: fused dense transform  h = silu(h @ Ws[l] + m @ Wm[l] + bL[l])
// 64-row x 128-col tile per block, 256 threads, each thread 8x4 outputs.
// In-place on h is safe: a block only writes the rows it read.
// ---------------------------------------------------------------------------
__global__ __launch_bounds__(256) void gemm_kernel(float* __restrict__ h,
                                                   const float* __restrict__ m,
                                                   const float* __restrict__ Ws,
                                                   const float* __restrict__ Wm,
                                                   const float* __restrict__ bL,
                                                   int l) {
    int r0 = blockIdx.x * 64;          // grid = 64000/64 = 1000
    int tid = threadIdx.x;
    int cg = tid & 31;                 // col group: cols cg*4 .. cg*4+3
    int rg = tid >> 5;                 // row group: rows rg*8 .. rg*8+7

    const float* WsL = Ws + (size_t)l * D_ * D_;
    const float* WmL = Wm + (size_t)l * D_ * D_;

    __shared__ float At[64][D_ + 4];

    float acc[8][4];
#pragma unroll
    for (int r = 0; r < 8; ++r)
#pragma unroll
        for (int cc = 0; cc < 4; ++cc) acc[r][cc] = 0.0f;

    for (int ph = 0; ph < 2; ++ph) {
        const float* A  = ph ? m : h;
        const float* Bm = ph ? WmL : WsL;
        __syncthreads();   // all reads of previous tile done
        for (int idx = tid; idx < 64 * 32; idx += 256) {
            int rr = idx >> 5;
            int cv = (idx & 31) * 4;
            float4 v = *(const float4*)&A[((size_t)(r0 + rr)) * D_ + cv];
            *(float4*)&At[rr][cv] = v;
        }
        __syncthreads();

#pragma unroll 4
        for (int k = 0; k < D_; ++k) {
            float4 b = *(const float4*)&Bm[(size_t)k * D_ + (cg << 2)];
            float a[8];
#pragma unroll
            for (int rr = 0; rr < 8; ++rr) a[rr] = At[rg * 8 + rr][k];
#pragma unroll
            for (int rr = 0; rr < 8; ++rr) {
                acc[rr][0] += a[rr] * b.x;
                acc[rr][1] += a[rr] * b.y;
                acc[rr][2] += a[rr] * b.z;
                acc[rr][3] += a[rr] * b.w;
            }
        }
    }

    const float* bl = bL + (size_t)l * D_;
    float4 bias = *(const float4*)&bl[cg << 2];
#pragma unroll
    for (int rr = 0; rr < 8; ++rr) {
        int row = r0 + rg * 8 + rr;
        float4 o;
        o.x = silu_f(acc[rr][0] + bias.x);
        o.y = silu_f(acc[rr][1] + bias.y);
        o.z = silu_f(acc[rr][2] + bias.z);
        o.w = silu_f(acc[rr][3] + bias.w);
        *(float4*)&h[(size_t)row * D_ + (cg << 2)] = o;
    }
}

// ---------------------------------------------------------------------------
// K4: global mean pool + output projection
// ---------------------------------------------------------------------------
__global__ __launch_bounds__(128) void pool_kernel(const float* __restrict__ h,
                                                   const float* __restrict__ Wo,
                                                   float* __restrict__ out) {
    int g = blockIdx.x;
    int dd = threadIdx.x;
    float s = 0.0f;
    const float* hg = h + (size_t)g * N_ * D_;
    for (int i = 0; i < N_; ++i) s += hg[(size_t)i * D_ + dd];
    __shared__ float pooled[D_];
    pooled[dd] = s * (1.0f / (float)N_);
    __syncthreads();
    float acc = 0.0f;
    for (int k = 0; k < D_; ++k) acc += pooled[k] * Wo[(size_t)k * D_ + dd];
    out[(size_t)g * D_ + dd] = acc;
}

// ---------------------------------------------------------------------------
extern "C" void kernel_launch(void* const* d_in, const int* in_sizes, int n_in,
                              void* d_out, int out_size, void* d_ws, size_t ws_size,
                              hipStream_t stream) {
    (void)in_sizes; (void)n_in; (void)out_size; (void)ws_size;
    const float* x  = (const float*)d_in[0];
    const float* Wn = (const float*)d_in[1];
    const float* bn = (const float*)d_in[2];
    const float* Ws = (const float*)d_in[3];
    const float* Wm = (const float*)d_in[4];
    const float* bL = (const float*)d_in[5];
    const float* we = (const float*)d_in[6];
    const float* be = (const float*)d_in[7];
    const float* Wo = (const float*)d_in[8];
    float* out = (float*)d_out;

    char* w = (char*)d_ws;
    uint32_t* adj = (uint32_t*)w;
    float* h = (float*)(w + ADJ_BYTES);
    float* m = (float*)(w + ADJ_BYTES + H_BYTES);

    hipMemsetAsync(adj, 0, ADJ_BYTES, stream);

    knn_kernel<<<G_ * ROWT, 256, 0, stream>>>(x, adj);
    enc_kernel<<<(G_ * N_ * D_) / 256, 256, 0, stream>>>(x, Wn, bn, h);

    for (int l = 0; l < L_; ++l) {
        agg_kernel<<<G_ * ROWT, 256, 0, stream>>>(x, adj, h, m, we, be, l);
        gemm_kernel<<<(G_ * N_) / 64, 256, 0, stream>>>(h, m, Ws, Wm, bL, l);
    }

    pool_kernel<<<G_, 128, 0, stream>>>(h, Wo, out);
}

// Round 2
// 1985.364 us; speedup vs baseline: 1.3070x; 1.3070x over previous
//
#include <hip/hip_runtime.h>
#include <hip/hip_bf16.h>
#include <stdint.h>

// Problem constants (S=8, B=16, N=500, D=128, K=50, L=6)
#define G_      128
#define N_      500
#define D_      128
#define K_      50
#define L_      6
#define NW_     16           // adjacency words per row (512 bits >= 500)
#define ROWT    125          // row tiles per graph (4 rows/block) in knn
#define STRIDE_ 160          // max symmetric degree (mean ~75, 160 is ~7 sigma)
#define HALF_   250          // rows per agg staging pass / per agg block

#define ADJ_BYTES ((size_t)G_ * N_ * NW_ * 4)        //  4,096,000
#define EJ_BYTES  ((size_t)G_ * N_ * STRIDE_ * 2)    // 20,480,000
#define ED_BYTES  ((size_t)G_ * N_ * STRIDE_ * 4)    // 40,960,000
#define EW_BYTES  ED_BYTES                           // 40,960,000
#define DS_BYTES  ((size_t)G_ * N_ * 4)              //    256,000
#define H_BYTES   ((size_t)G_ * N_ * D_ * 4)         // 32,768,000

__device__ __forceinline__ float silu_f(float z) {
    return z / (1.0f + expf(-z));
}

// ---------------------------------------------------------------------------
// K0: kNN via exact bitwise binary-search selection of the 50th smallest
// distance, then mark d < V plus index-ordered ties. One wave per row.
// Writes directed adjacency bitmask with plain stores (no atomics).
// ---------------------------------------------------------------------------
__global__ __launch_bounds__(256) void knn_kernel(const float* __restrict__ x,
                                                  uint32_t* __restrict__ adj) {
    int g    = blockIdx.x / ROWT;
    int tile = blockIdx.x % ROWT;
    int wv   = threadIdx.x >> 6;
    int lane = threadIdx.x & 63;
    int i    = tile * 4 + wv;    // 0..499

    __shared__ float2 c[N_];
    for (int t = threadIdx.x; t < N_; t += 256)
        c[t] = ((const float2*)x)[(size_t)g * N_ + t];
    __syncthreads();

    float2 ci = c[i];
    uint32_t kb[8];
#pragma unroll
    for (int r = 0; r < 8; ++r) {
        int j = lane + r * 64;
        float dv;
        if (j < N_ && j != i) {
            float dx = ci.x - c[j].x, dy = ci.y - c[j].y;
            dv = sqrtf(dx * dx + dy * dy + 1e-12f);
        } else {
            dv = 3.0e38f;
        }
        kb[r] = __float_as_uint(dv);   // positive floats: bits are order-preserving
    }

    // V = 50th smallest key = largest T with #{key < T} < 50, built MSB-first.
    uint32_t prefix = 0;
    for (int bit = 30; bit >= 0; --bit) {
        uint32_t cand = prefix | (1u << bit);
        int cnt = 0;
#pragma unroll
        for (int r = 0; r < 8; ++r)
            cnt += __popcll(__ballot(kb[r] < cand));
        if (cnt < K_) prefix = cand;
    }

    unsigned long long sel[8];
    int cntless = 0;
#pragma unroll
    for (int r = 0; r < 8; ++r) {
        sel[r] = __ballot(kb[r] < prefix);
        cntless += __popcll(sel[r]);
    }
    int rem = K_ - cntless;   // >=1 ties at V to take, lowest index first
#pragma unroll
    for (int r = 0; r < 8; ++r) {
        unsigned long long tb = __ballot(kb[r] == prefix);
        while (rem > 0 && tb) {
            unsigned long long lb = tb & (~tb + 1ull);
            sel[r] |= lb;
            tb ^= lb;
            --rem;
        }
    }

    uint32_t* arow = adj + ((size_t)g * N_ + i) * NW_;
#pragma unroll
    for (int r = 0; r < 8; ++r) {
        if (lane == 2 * r)     arow[2 * r]     = (uint32_t)sel[r];
        if (lane == 2 * r + 1) arow[2 * r + 1] = (uint32_t)(sel[r] >> 32);
    }
}

// ---------------------------------------------------------------------------
// K0b: symmetrize adjacency in LDS, emit per-row sorted (j, dist) edge lists
// plus packed deg|split (split = #edges with j < HALF_). One block per graph.
// ---------------------------------------------------------------------------
__global__ __launch_bounds__(512) void edge_kernel(const float* __restrict__ x,
                                                   const uint32_t* __restrict__ adj,
                                                   uint16_t* __restrict__ ej,
                                                   float* __restrict__ ed,
                                                   uint32_t* __restrict__ degsplit) {
    int g   = blockIdx.x;
    int tid = threadIdx.x;
    __shared__ uint32_t am[N_][NW_];   // 32,000 B
    __shared__ float2   c[N_];         //  4,000 B

    for (int t = tid; t < N_; t += 512)
        c[t] = ((const float2*)x)[(size_t)g * N_ + t];
    const uint32_t* ag = adj + (size_t)g * N_ * NW_;
    for (int t = tid; t < N_ * NW_; t += 512)
        ((uint32_t*)am)[t] = ag[t];
    __syncthreads();

    // A = A | A^T  (buffer results, then write back after barrier)
    uint32_t buf[16];
    int cnt = 0;
    for (int idx = tid; idx < N_ * NW_; idx += 512) {
        int ii = idx >> 4, w = idx & 15;
        uint32_t v  = am[ii][w];
        int jb      = w << 5;
        int jmax    = (jb + 32 <= N_) ? 32 : (N_ - jb);
        uint32_t wi = (uint32_t)ii >> 5, bi = ii & 31;
        for (int b = 0; b < jmax; ++b)
            v |= ((am[jb + b][wi] >> bi) & 1u) << b;
        buf[cnt++] = v;
    }
    __syncthreads();
    cnt = 0;
    for (int idx = tid; idx < N_ * NW_; idx += 512)
        am[idx >> 4][idx & 15] = buf[cnt++];
    __syncthreads();

    // edge-list emission: wave per row; lane w (<16) owns bitmask word w
    int wv = tid >> 6, lane = tid & 63;
    for (int i = wv; i < N_; i += 8) {
        uint32_t w = (lane < NW_) ? am[i][lane] : 0u;
        int pc   = __popc(w);
        int pref = pc;
#pragma unroll
        for (int off = 1; off < 16; off <<= 1) {
            int o = __shfl_up(pref, off);
            if (lane >= off) pref += o;
        }
        int deg   = __shfl(pref, 15);
        int p7    = __popc(w & 0x03FFFFFFu);           // word 7 bits j=224..249
        int split = __shfl(pref, 6) + __shfl(p7, 7);   // #edges with j < 250
        int base  = pref - pc;                          // exclusive prefix
        float2 ci = c[i];
        size_t eoff = ((size_t)g * N_ + i) * STRIDE_;
        uint32_t ww = w;
        int slot = base;
        while (ww) {
            int b = __ffs(ww) - 1;
            ww &= ww - 1;
            int j = (lane << 5) + b;
            float dx = ci.x - c[j].x, dy = ci.y - c[j].y;
            float dd = sqrtf(dx * dx + dy * dy + 1e-12f);
            if (slot < STRIDE_) {
                ej[eoff + slot] = (uint16_t)j;
                ed[eoff + slot] = dd;
            }
            ++slot;
        }
        if (lane == 0) {
            int dc = deg   > STRIDE_ ? STRIDE_ : deg;
            int sc = split > STRIDE_ ? STRIDE_ : split;
            degsplit[(size_t)g * N_ + i] = (uint32_t)dc | ((uint32_t)sc << 16);
        }
    }
}

// ---------------------------------------------------------------------------
// K1: h0 = silu(coords @ Wn + bn)
// ---------------------------------------------------------------------------
__global__ __launch_bounds__(256) void enc_kernel(const float* __restrict__ x,
                                                  const float* __restrict__ Wn,
                                                  const float* __restrict__ bn,
                                                  float* __restrict__ h) {
    int idx = blockIdx.x * 256 + threadIdx.x;
    int dd  = idx & (D_ - 1);
    int row = idx >> 7;
    float x0 = x[(size_t)row * 2];
    float x1 = x[(size_t)row * 2 + 1];
    float z = x0 * Wn[dd] + x1 * Wn[D_ + dd] + bn[dd];
    h[idx] = silu_f(z);
}

// ---------------------------------------------------------------------------
// K2: sparse aggregation with full-graph h staged in LDS (f32, two 250-row
// passes). 2 blocks per graph; each block owns 250 output rows.
// Phase 0 computes each edge's weight ONCE (block-local, via global ew).
// dynamic LDS = 250*128*4 = 128000 B.
// ---------------------------------------------------------------------------
__global__ __launch_bounds__(512) void agg_kernel(const float* __restrict__ h,
                                                  const uint16_t* __restrict__ ej,
                                                  const float* __restrict__ ed,
                                                  float* __restrict__ ew,
                                                  const uint32_t* __restrict__ degsplit,
                                                  float* __restrict__ m,
                                                  const float* __restrict__ we,
                                                  const float* __restrict__ be,
                                                  int l) {
    int g    = blockIdx.x >> 1;
    int hs   = blockIdx.x & 1;
    int row0 = hs * HALF_;
    extern __shared__ float hb[];   // [HALF_][D_]
    int tid = threadIdx.x, wv = tid >> 6, lane = tid & 63;

    const float* hg = h + (size_t)g * N_ * D_;
    float*       mg = m + (size_t)g * N_ * D_;
    float wel = we[l], bel = be[l];

    // phase 0: per-edge weights for this block's 250 rows (coalesced)
    size_t ebase = ((size_t)g * N_ + row0) * STRIDE_;
    for (int s = tid; s < HALF_ * STRIDE_; s += 512) {
        int r    = s / STRIDE_;
        int slot = s - r * STRIDE_;
        int deg  = degsplit[(size_t)g * N_ + row0 + r] & 0xffff;
        if (slot < deg) {
            float d = ed[ebase + s];
            float z = wel * d + bel;
            ew[ebase + s] = z / (1.0f + expf(-z));
        }
    }
    __threadfence_block();

    // ---- pass A: stage h rows [0, 250), accumulate edges with j < 250 ----
    __syncthreads();
    for (int t = tid; t < HALF_ * (D_ / 4); t += 512)
        ((float4*)hb)[t] = ((const float4*)hg)[t];
    __syncthreads();

    for (int r = wv; r < HALF_; r += 8) {
        int i = row0 + r;
        uint32_t dsp = degsplit[(size_t)g * N_ + i];
        int split = dsp >> 16;
        size_t eoff = ((size_t)g * N_ + i) * STRIDE_;
        float ax = 0.f, ay = 0.f;
#pragma unroll 4
        for (int e = 0; e < split; ++e) {
            int j     = ej[eoff + e];
            float wgt = ew[eoff + e];
            float2 hj = *(const float2*)&hb[j * D_ + lane * 2];
            ax += wgt * hj.x;
            ay += wgt * hj.y;
        }
        *(float2*)&mg[(size_t)i * D_ + lane * 2] = make_float2(ax, ay);
    }

    // ---- pass B: stage h rows [250, 500), accumulate edges with j >= 250 --
    __syncthreads();
    for (int t = tid; t < (N_ - HALF_) * (D_ / 4); t += 512)
        ((float4*)hb)[t] = ((const float4*)(hg + HALF_ * D_))[t];
    __syncthreads();

    for (int r = wv; r < HALF_; r += 8) {
        int i = row0 + r;
        uint32_t dsp = degsplit[(size_t)g * N_ + i];
        int deg = dsp & 0xffff, split = dsp >> 16;
        size_t eoff = ((size_t)g * N_ + i) * STRIDE_;
        float2 acc = *(const float2*)&mg[(size_t)i * D_ + lane * 2];
        float ax = acc.x, ay = acc.y;
#pragma unroll 4
        for (int e = split; e < deg; ++e) {
            int j     = ej[eoff + e] - HALF_;
            float wgt = ew[eoff + e];
            float2 hj = *(const float2*)&hb[j * D_ + lane * 2];
            ax += wgt * hj.x;
            ay += wgt * hj.y;
        }
        *(float2*)&mg[(size_t)i * D_ + lane * 2] = make_float2(ax, ay);
    }
}

// ---------------------------------------------------------------------------
// K3: fused dense transform  h = silu(h @ Ws[l] + m @ Wm[l] + bL[l])
// ---------------------------------------------------------------------------
__global__ __launch_bounds__(256) void gemm_kernel(float* __restrict__ h,
                                                   const float* __restrict__ m,
                                                   const float* __restrict__ Ws,
                                                   const float* __restrict__ Wm,
                                                   const float* __restrict__ bL,
                                                   int l) {
    int r0 = blockIdx.x * 64;
    int tid = threadIdx.x;
    int cg = tid & 31;
    int rg = tid >> 5;

    const float* WsL = Ws + (size_t)l * D_ * D_;
    const float* WmL = Wm + (size_t)l * D_ * D_;

    __shared__ float At[64][D_ + 4];

    float acc[8][4];
#pragma unroll
    for (int r = 0; r < 8; ++r)
#pragma unroll
        for (int cc = 0; cc < 4; ++cc) acc[r][cc] = 0.0f;

    for (int ph = 0; ph < 2; ++ph) {
        const float* A  = ph ? m : h;
        const float* Bm = ph ? WmL : WsL;
        __syncthreads();
        for (int idx = tid; idx < 64 * 32; idx += 256) {
            int rr = idx >> 5;
            int cv = (idx & 31) * 4;
            float4 v = *(const float4*)&A[((size_t)(r0 + rr)) * D_ + cv];
            *(float4*)&At[rr][cv] = v;
        }
        __syncthreads();

#pragma unroll 4
        for (int k = 0; k < D_; ++k) {
            float4 b = *(const float4*)&Bm[(size_t)k * D_ + (cg << 2)];
            float a[8];
#pragma unroll
            for (int rr = 0; rr < 8; ++rr) a[rr] = At[rg * 8 + rr][k];
#pragma unroll
            for (int rr = 0; rr < 8; ++rr) {
                acc[rr][0] += a[rr] * b.x;
                acc[rr][1] += a[rr] * b.y;
                acc[rr][2] += a[rr] * b.z;
                acc[rr][3] += a[rr] * b.w;
            }
        }
    }

    const float* bl = bL + (size_t)l * D_;
    float4 bias = *(const float4*)&bl[cg << 2];
#pragma unroll
    for (int rr = 0; rr < 8; ++rr) {
        int row = r0 + rg * 8 + rr;
        float4 o;
        o.x = silu_f(acc[rr][0] + bias.x);
        o.y = silu_f(acc[rr][1] + bias.y);
        o.z = silu_f(acc[rr][2] + bias.z);
        o.w = silu_f(acc[rr][3] + bias.w);
        *(float4*)&h[(size_t)row * D_ + (cg << 2)] = o;
    }
}

// ---------------------------------------------------------------------------
// K4: global mean pool + output projection
// ---------------------------------------------------------------------------
__global__ __launch_bounds__(128) void pool_kernel(const float* __restrict__ h,
                                                   const float* __restrict__ Wo,
                                                   float* __restrict__ out) {
    int g = blockIdx.x;
    int dd = threadIdx.x;
    float s = 0.0f;
    const float* hg = h + (size_t)g * N_ * D_;
    for (int i = 0; i < N_; ++i) s += hg[(size_t)i * D_ + dd];
    __shared__ float pooled[D_];
    pooled[dd] = s * (1.0f / (float)N_);
    __syncthreads();
    float acc = 0.0f;
    for (int k = 0; k < D_; ++k) acc += pooled[k] * Wo[(size_t)k * D_ + dd];
    out[(size_t)g * D_ + dd] = acc;
}

// ---------------------------------------------------------------------------
extern "C" void kernel_launch(void* const* d_in, const int* in_sizes, int n_in,
                              void* d_out, int out_size, void* d_ws, size_t ws_size,
                              hipStream_t stream) {
    (void)in_sizes; (void)n_in; (void)out_size; (void)ws_size;
    const float* x  = (const float*)d_in[0];
    const float* Wn = (const float*)d_in[1];
    const float* bn = (const float*)d_in[2];
    const float* Ws = (const float*)d_in[3];
    const float* Wm = (const float*)d_in[4];
    const float* bL = (const float*)d_in[5];
    const float* we = (const float*)d_in[6];
    const float* be = (const float*)d_in[7];
    const float* Wo = (const float*)d_in[8];
    float* out = (float*)d_out;

    char* w = (char*)d_ws;
    uint32_t* adj   = (uint32_t*)w;  w += ADJ_BYTES;
    uint16_t* ej    = (uint16_t*)w;  w += EJ_BYTES;
    float*    ed    = (float*)w;     w += ED_BYTES;
    float*    ew    = (float*)w;     w += EW_BYTES;
    uint32_t* dsarr = (uint32_t*)w;  w += DS_BYTES;
    float*    h     = (float*)w;     w += H_BYTES;
    float*    m     = (float*)w;

    hipFuncSetAttribute((const void*)agg_kernel,
                        hipFuncAttributeMaxDynamicSharedMemorySize, HALF_ * D_ * 4);

    knn_kernel<<<G_ * ROWT, 256, 0, stream>>>(x, adj);
    edge_kernel<<<G_, 512, 0, stream>>>(x, adj, ej, ed, dsarr);
    enc_kernel<<<(G_ * N_ * D_) / 256, 256, 0, stream>>>(x, Wn, bn, h);

    for (int l = 0; l < L_; ++l) {
        agg_kernel<<<G_ * 2, 512, HALF_ * D_ * 4, stream>>>(h, ej, ed, ew, dsarr, m, we, be, l);
        gemm_kernel<<<(G_ * N_) / 64, 256, 0, stream>>>(h, m, Ws, Wm, bL, l);
    }

    pool_kernel<<<G_, 128, 0, stream>>>(h, Wo, out);
}

// Round 3
// 618.688 us; speedup vs baseline: 4.1940x; 3.2090x over previous
//
#include <hip/hip_runtime.h>
#include <hip/hip_bf16.h>
#include <stdint.h>

// Problem constants (S=8, B=16, N=500, D=128, K=50, L=6)
#define G_   128
#define N_   500
#define NP_  512          // padded N (stride)
#define D_   128
#define K_   50
#define L_   6
#define NW_  16           // adjacency words per row
#define ROWT 125

typedef __attribute__((ext_vector_type(8))) short bf16x8;
typedef __attribute__((ext_vector_type(4))) float f32x4;

#define ADJ_BYTES  ((size_t)G_ * N_ * NW_ * 4)
#define ADJS_BYTES ((size_t)G_ * NP_ * NW_ * 4)
#define HB_BYTES   ((size_t)G_ * NP_ * D_ * 2)     // bf16 h or hT buffer
#define WT_BYTES   ((size_t)L_ * D_ * D_ * 2)      // bf16 transposed weights

__device__ __forceinline__ float silu_f(float z) {
    return z * __builtin_amdgcn_rcpf(1.0f + __expf(-z));
}
__device__ __forceinline__ unsigned short f2bf(float f) {
    uint32_t u = __float_as_uint(f);
    u += 0x7fffu + ((u >> 16) & 1u);
    return (unsigned short)(u >> 16);
}
__device__ __forceinline__ float bf2f(unsigned short s) {
    return __uint_as_float(((uint32_t)s) << 16);
}

// ---------------------------------------------------------------------------
// K0: kNN via exact bitwise binary-search of the 50th smallest distance.
// One wave per row; writes directed adjacency bitmask (plain stores).
// ---------------------------------------------------------------------------
__global__ __launch_bounds__(256) void knn_kernel(const float* __restrict__ x,
                                                  uint32_t* __restrict__ adj) {
    int g    = blockIdx.x / ROWT;
    int tile = blockIdx.x % ROWT;
    int wv   = threadIdx.x >> 6;
    int lane = threadIdx.x & 63;
    int i    = tile * 4 + wv;

    __shared__ float2 c[N_];
    for (int t = threadIdx.x; t < N_; t += 256)
        c[t] = ((const float2*)x)[(size_t)g * N_ + t];
    __syncthreads();

    float2 ci = c[i];
    uint32_t kb[8];
#pragma unroll
    for (int r = 0; r < 8; ++r) {
        int j = lane + r * 64;
        float dv;
        if (j < N_ && j != i) {
            float dx = ci.x - c[j].x, dy = ci.y - c[j].y;
            dv = sqrtf(dx * dx + dy * dy + 1e-12f);
        } else {
            dv = 3.0e38f;
        }
        kb[r] = __float_as_uint(dv);
    }

    uint32_t prefix = 0;
    for (int bit = 30; bit >= 0; --bit) {
        uint32_t cand = prefix | (1u << bit);
        int cnt = 0;
#pragma unroll
        for (int r = 0; r < 8; ++r)
            cnt += __popcll(__ballot(kb[r] < cand));
        if (cnt < K_) prefix = cand;
    }

    unsigned long long sel[8];
    int cntless = 0;
#pragma unroll
    for (int r = 0; r < 8; ++r) {
        sel[r] = __ballot(kb[r] < prefix);
        cntless += __popcll(sel[r]);
    }
    int rem = K_ - cntless;
#pragma unroll
    for (int r = 0; r < 8; ++r) {
        unsigned long long tb = __ballot(kb[r] == prefix);
        while (rem > 0 && tb) {
            unsigned long long lb = tb & (~tb + 1ull);
            sel[r] |= lb;
            tb ^= lb;
            --rem;
        }
    }

    uint32_t* arow = adj + ((size_t)g * N_ + i) * NW_;
#pragma unroll
    for (int r = 0; r < 8; ++r) {
        if (lane == 2 * r)     arow[2 * r]     = (uint32_t)sel[r];
        if (lane == 2 * r + 1) arow[2 * r + 1] = (uint32_t)(sel[r] >> 32);
    }
}

// ---------------------------------------------------------------------------
// K0b: symmetrize bitmask (A |= A^T) into padded adjS (rows 500..511 = 0).
// ---------------------------------------------------------------------------
__global__ __launch_bounds__(512) void sym_kernel(const uint32_t* __restrict__ adj,
                                                  uint32_t* __restrict__ adjS) {
    int g = blockIdx.x, tid = threadIdx.x;
    __shared__ uint32_t am[N_][NW_];
    const uint32_t* ag = adj + (size_t)g * N_ * NW_;
    for (int t = tid; t < N_ * NW_; t += 512) ((uint32_t*)am)[t] = ag[t];
    __syncthreads();
    uint32_t* og = adjS + (size_t)g * NP_ * NW_;
    for (int idx = tid; idx < N_ * NW_; idx += 512) {
        int ii = idx >> 4, w = idx & 15;
        uint32_t v = am[ii][w];
        int jb = w << 5;
        int jmax = (jb + 32 <= N_) ? 32 : (N_ - jb);
        uint32_t wi = (uint32_t)ii >> 5, bi = ii & 31;
        for (int b = 0; b < jmax; ++b)
            v |= ((am[jb + b][wi] >> bi) & 1u) << b;
        og[ii * NW_ + w] = v;
    }
    for (int idx = N_ * NW_ + tid; idx < NP_ * NW_; idx += 512)
        og[idx] = 0;
}

// ---------------------------------------------------------------------------
// K0c: transpose weights to bf16: WT[l][dout][din] = bf16(W[l][din][dout])
// ---------------------------------------------------------------------------
__global__ __launch_bounds__(256) void wprep_kernel(const float* __restrict__ Ws,
                                                    const float* __restrict__ Wm,
                                                    unsigned short* __restrict__ WsT,
                                                    unsigned short* __restrict__ WmT) {
    int idx = blockIdx.x * 256 + threadIdx.x;   // < 2*6*16384
    int half = idx >= L_ * D_ * D_;
    int r = half ? idx - L_ * D_ * D_ : idx;
    int l = r >> 14, rr = r & 16383, dout = rr >> 7, din = rr & 127;
    const float* W = half ? Wm : Ws;
    unsigned short* O = half ? WmT : WsT;
    O[r] = f2bf(W[(size_t)l * 16384 + din * 128 + dout]);
}

// ---------------------------------------------------------------------------
// K1: h0 = silu(coords @ Wn + bn), written bf16 as h[i][d] AND hT[d][i]
// (hT pad cols 500..511 zeroed).
// ---------------------------------------------------------------------------
__global__ __launch_bounds__(256) void enc_kernel(const float* __restrict__ x,
                                                  const float* __restrict__ Wn,
                                                  const float* __restrict__ bn,
                                                  unsigned short* __restrict__ h,
                                                  unsigned short* __restrict__ hT) {
    int g = blockIdx.x, tid = threadIdx.x;
    __shared__ float2 c[N_];
    for (int t = tid; t < N_; t += 256)
        c[t] = ((const float2*)x)[(size_t)g * N_ + t];
    __syncthreads();
    // h[i][d]
    for (int o = tid; o < N_ * 16; o += 256) {
        int i = o >> 4, d0 = (o & 15) * 8;
        float2 ci = c[i];
        unsigned short u[8];
#pragma unroll
        for (int e = 0; e < 8; ++e) {
            int d = d0 + e;
            u[e] = f2bf(silu_f(ci.x * Wn[d] + ci.y * Wn[D_ + d] + bn[d]));
        }
        *(uint4*)&h[((size_t)g * NP_ + i) * D_ + d0] = *(uint4*)u;
    }
    // hT[d][i] + pad zeros
    for (int o = tid; o < D_ * 64; o += 256) {
        int d = o >> 6, io = o & 63;
        float w0 = Wn[d], w1 = Wn[D_ + d], b = bn[d];
        unsigned short u[8];
#pragma unroll
        for (int e = 0; e < 8; ++e) {
            int i = io * 8 + e;
            unsigned short val = 0;
            if (i < N_) {
                float2 ci = c[i];
                val = f2bf(silu_f(ci.x * w0 + ci.y * w1 + b));
            }
            u[e] = val;
        }
        *(uint4*)&hT[((size_t)g * D_ + d) * NP_ + io * 8] = *(uint4*)u;
    }
}

// ---------------------------------------------------------------------------
// K2: fused layer: mT = hT @ gateT (gate computed on the fly, MFMA), then
// h_new = silu([h|m] @ [WsT|WmT]^T + b) as one 128x128x256 MFMA GEMM.
// Grid: G*4 (graph x 128-row i-tile). 8 waves = 2(dout) x 4(i).
// Dynamic LDS 128KB: phase1 {c,am,hTA,gateB} 44KB | phase2 {Astk,Bstk} 128KB.
// ---------------------------------------------------------------------------
__global__ __launch_bounds__(512, 2) void layer_kernel(
    const uint32_t* __restrict__ adjS,
    const float* __restrict__ x,
    const unsigned short* __restrict__ hin,    // [G][NP_][D_]
    const unsigned short* __restrict__ hinT,   // [G][D_][NP_]
    unsigned short* __restrict__ hout,
    unsigned short* __restrict__ houtT,
    const unsigned short* __restrict__ WsT,    // [L][dout][din] bf16
    const unsigned short* __restrict__ WmT,
    const float* __restrict__ bL,
    const float* __restrict__ we,
    const float* __restrict__ be, int l)
{
    int g  = blockIdx.x >> 2;
    int it = blockIdx.x & 3;
    int i0 = it * 128;
    int tid = threadIdx.x;
    int lane = tid & 63, wv = tid >> 6;
    int wrow = wv >> 2, wcol = wv & 3;   // wave tile: 64 d-rows x 32 i-cols

    extern __shared__ char lds[];
    float2*   c2    = (float2*)lds;              // [512]      4096 B
    uint32_t* am    = (uint32_t*)(lds + 4096);   // [128][16]  8192 B
    char*     hTA   = lds + 12288;               // [128][64] bf16 16384 B
    char*     gateB = lds + 28672;               // [128][64] bf16 16384 B (ends 45056)
    char*     Astk  = lds;                       // [128][256] bf16 65536 B (phase 2)
    char*     Bstk  = lds + 65536;               // [128][256] bf16 65536 B (disjoint!)

    // stage coords + this tile's adjacency rows
    for (int t = tid; t < N_; t += 512)
        c2[t] = ((const float2*)x)[(size_t)g * N_ + t];
    const uint32_t* aS = adjS + ((size_t)g * NP_ + i0) * NW_;
    for (int t = tid; t < 128 * NW_; t += 512) am[t] = aS[t];
    __syncthreads();

    float wel = we[l], bel = be[l];
    const unsigned short* hTg = hinT + (size_t)g * D_ * NP_;

    f32x4 acc[4][2];
#pragma unroll
    for (int a_ = 0; a_ < 4; ++a_)
#pragma unroll
        for (int b_ = 0; b_ < 2; ++b_)
            acc[a_][b_] = (f32x4){0.f, 0.f, 0.f, 0.f};

    // ---- phase 1: mT += hT_tile @ gateT_tile over 8 j-tiles of 64 ----
    for (int jt = 0; jt < 8; ++jt) {
        if (jt) __syncthreads();
        int j0t = jt * 64;
        // stage hTA [128 d][64 j] (swizzled)
#pragma unroll
        for (int p = 0; p < 2; ++p) {
            int o = tid + p * 512;
            int d = o >> 3, jo = o & 7;
            uint4 v = *(const uint4*)&hTg[(size_t)d * NP_ + j0t + jo * 8];
            int byt = (d << 7) + (jo << 4); byt ^= (d & 7) << 4;
            *(uint4*)(hTA + byt) = v;
        }
        // compute gate [128 i][64 j] bf16 (swizzled)
#pragma unroll
        for (int p = 0; p < 2; ++p) {
            int o = tid + p * 512;
            int il = o >> 3, jo = o & 7;
            int jb = j0t + jo * 8;
            uint32_t wbits = am[il * NW_ + (jb >> 5)];
            uint32_t b8 = (wbits >> (jb & 31)) & 0xffu;
            float2 ci = c2[i0 + il];
            unsigned short u[8];
#pragma unroll
            for (int e = 0; e < 8; ++e) {
                float2 cj = c2[jb + e];
                float dx = ci.x - cj.x, dy = ci.y - cj.y;
                float dist = __builtin_amdgcn_sqrtf(dx * dx + dy * dy + 1e-12f);
                float z = wel * dist + bel;
                float s = z * __builtin_amdgcn_rcpf(1.0f + __expf(-z));
                u[e] = ((b8 >> e) & 1u) ? f2bf(s) : (unsigned short)0;
            }
            int byt = (il << 7) + (jo << 4); byt ^= (il & 7) << 4;
            *(uint4*)(gateB + byt) = *(uint4*)u;
        }
        __syncthreads();
        // MFMA: acc[d-frag][i-frag] over k=64
#pragma unroll
        for (int kk = 0; kk < 64; kk += 32) {
            int kbyte = (kk + ((lane >> 4) << 3)) << 1;
            bf16x8 af[4], bfr[2];
#pragma unroll
            for (int fr = 0; fr < 4; ++fr) {
                int d = wrow * 64 + fr * 16 + (lane & 15);
                int byt = (d << 7) + kbyte; byt ^= (d & 7) << 4;
                af[fr] = *(const bf16x8*)(hTA + byt);
            }
#pragma unroll
            for (int fc = 0; fc < 2; ++fc) {
                int i = wcol * 32 + fc * 16 + (lane & 15);
                int byt = (i << 7) + kbyte; byt ^= (i & 7) << 4;
                bfr[fc] = *(const bf16x8*)(gateB + byt);
            }
#pragma unroll
            for (int fr = 0; fr < 4; ++fr)
#pragma unroll
                for (int fc = 0; fc < 2; ++fc)
                    acc[fr][fc] = __builtin_amdgcn_mfma_f32_16x16x32_bf16(
                        af[fr], bfr[fc], acc[fr][fc], 0, 0, 0);
        }
    }

    // ---- write m frags to Bstk k=128..255 (region disjoint from phase 1) ----
#pragma unroll
    for (int fr = 0; fr < 4; ++fr)
#pragma unroll
        for (int fc = 0; fc < 2; ++fc) {
            int dbase = wrow * 64 + fr * 16 + ((lane >> 4) << 2);
            int ib    = wcol * 32 + fc * 16 + (lane & 15);
            f32x4 v = acc[fr][fc];
            uint32_t p0 = (uint32_t)f2bf(v[0]) | ((uint32_t)f2bf(v[1]) << 16);
            uint32_t p1 = (uint32_t)f2bf(v[2]) | ((uint32_t)f2bf(v[3]) << 16);
            int byt = (ib << 9) + ((128 + dbase) << 1); byt ^= (ib & 7) << 4;
            *(uint32_t*)(Bstk + byt)     = p0;
            *(uint32_t*)(Bstk + byt + 4) = p1;
        }
    __syncthreads();   // phase-1 LDS reads done; now overwrite with Astk / Bstk-h

    // stage Astk = [WsT | WmT] [128 dout][256 k] (swizzled)
    const unsigned short* wsp = WsT + (size_t)l * D_ * D_;
    const unsigned short* wmp = WmT + (size_t)l * D_ * D_;
#pragma unroll
    for (int p = 0; p < 8; ++p) {
        int o = tid + p * 512;
        int dout = o >> 5, ko = o & 31;
        uint4 v;
        if (ko < 16) v = *(const uint4*)&wsp[dout * 128 + ko * 8];
        else         v = *(const uint4*)&wmp[dout * 128 + (ko - 16) * 8];
        int byt = (dout << 9) + (ko << 4); byt ^= (dout & 7) << 4;
        *(uint4*)(Astk + byt) = v;
    }
    // stage Bstk h-half [128 i][k<128] (zero-fill rows >= N_)
    const unsigned short* hg = hin + (size_t)g * NP_ * D_;
#pragma unroll
    for (int p = 0; p < 4; ++p) {
        int o = tid + p * 512;
        int il = o >> 4, ko = o & 15;
        int gi = i0 + il;
        uint4 v = make_uint4(0u, 0u, 0u, 0u);
        if (gi < N_) v = *(const uint4*)&hg[(size_t)gi * D_ + ko * 8];
        int byt = (il << 9) + (ko << 4); byt ^= (il & 7) << 4;
        *(uint4*)(Bstk + byt) = v;
    }
    __syncthreads();

    // ---- phase 2: h_new^T = Astk @ Bstk^T  (128x128, K=256) ----
    f32x4 acc2[4][2];
#pragma unroll
    for (int a_ = 0; a_ < 4; ++a_)
#pragma unroll
        for (int b_ = 0; b_ < 2; ++b_)
            acc2[a_][b_] = (f32x4){0.f, 0.f, 0.f, 0.f};

    for (int kk = 0; kk < 256; kk += 32) {
        int kbyte = (kk + ((lane >> 4) << 3)) << 1;
        bf16x8 af[4], bfr[2];
#pragma unroll
        for (int fr = 0; fr < 4; ++fr) {
            int d = wrow * 64 + fr * 16 + (lane & 15);
            int byt = (d << 9) + kbyte; byt ^= (d & 7) << 4;
            af[fr] = *(const bf16x8*)(Astk + byt);
        }
#pragma unroll
        for (int fc = 0; fc < 2; ++fc) {
            int i = wcol * 32 + fc * 16 + (lane & 15);
            int byt = (i << 9) + kbyte; byt ^= (i & 7) << 4;
            bfr[fc] = *(const bf16x8*)(Bstk + byt);
        }
#pragma unroll
        for (int fr = 0; fr < 4; ++fr)
#pragma unroll
            for (int fc = 0; fc < 2; ++fc)
                acc2[fr][fc] = __builtin_amdgcn_mfma_f32_16x16x32_bf16(
                    af[fr], bfr[fc], acc2[fr][fc], 0, 0, 0);
    }

    // ---- epilogue: bias + silu, write hout[i][d] and houtT[d][i] ----
    const float* blp = bL + (size_t)l * D_;
#pragma unroll
    for (int fr = 0; fr < 4; ++fr)
#pragma unroll
        for (int fc = 0; fc < 2; ++fc) {
            int dbase = wrow * 64 + fr * 16 + ((lane >> 4) << 2);
            int gi = i0 + wcol * 32 + fc * 16 + (lane & 15);
            f32x4 v = acc2[fr][fc];
            float4 bias = *(const float4*)&blp[dbase];
            float o0 = silu_f(v[0] + bias.x);
            float o1 = silu_f(v[1] + bias.y);
            float o2 = silu_f(v[2] + bias.z);
            float o3 = silu_f(v[3] + bias.w);
            size_t tbase = ((size_t)g * D_ + dbase) * NP_ + gi;
            if (gi < N_) {
                uint32_t q0 = (uint32_t)f2bf(o0) | ((uint32_t)f2bf(o1) << 16);
                uint32_t q1 = (uint32_t)f2bf(o2) | ((uint32_t)f2bf(o3) << 16);
                *(uint2*)&hout[((size_t)g * NP_ + gi) * D_ + dbase] = make_uint2(q0, q1);
                houtT[tbase]           = f2bf(o0);
                houtT[tbase + NP_]     = f2bf(o1);
                houtT[tbase + 2 * NP_] = f2bf(o2);
                houtT[tbase + 3 * NP_] = f2bf(o3);
            } else {
                houtT[tbase]           = 0;
                houtT[tbase + NP_]     = 0;
                houtT[tbase + 2 * NP_] = 0;
                houtT[tbase + 3 * NP_] = 0;
            }
        }
}

// ---------------------------------------------------------------------------
// K4: global mean pool + output projection (f32 accumulation from bf16 h)
// ---------------------------------------------------------------------------
__global__ __launch_bounds__(256) void pool_kernel(const unsigned short* __restrict__ h,
                                                   const float* __restrict__ Wo,
                                                   float* __restrict__ out) {
    int g = blockIdx.x, tid = threadIdx.x;
    const unsigned short* hg = h + (size_t)g * NP_ * D_;
    float a8[8];
#pragma unroll
    for (int e = 0; e < 8; ++e) a8[e] = 0.f;
    int d0 = (tid & 15) * 8;
    for (int i = tid >> 4; i < N_; i += 16) {
        uint4 v = *(const uint4*)&hg[(size_t)i * D_ + d0];
        const unsigned short* pu = (const unsigned short*)&v;
#pragma unroll
        for (int e = 0; e < 8; ++e) a8[e] += bf2f(pu[e]);
    }
    __shared__ float red[16][D_];
#pragma unroll
    for (int e = 0; e < 8; ++e) red[tid >> 4][d0 + e] = a8[e];
    __syncthreads();
    __shared__ float pooled[D_];
    if (tid < D_) {
        float s = 0.f;
#pragma unroll
        for (int grp = 0; grp < 16; ++grp) s += red[grp][tid];
        pooled[tid] = s * (1.0f / (float)N_);
    }
    __syncthreads();
    if (tid < D_) {
        float acc = 0.f;
        for (int k = 0; k < D_; ++k) acc += pooled[k] * Wo[(size_t)k * D_ + tid];
        out[(size_t)g * D_ + tid] = acc;
    }
}

// ---------------------------------------------------------------------------
extern "C" void kernel_launch(void* const* d_in, const int* in_sizes, int n_in,
                              void* d_out, int out_size, void* d_ws, size_t ws_size,
                              hipStream_t stream) {
    (void)in_sizes; (void)n_in; (void)out_size; (void)ws_size;
    const float* x  = (const float*)d_in[0];
    const float* Wn = (const float*)d_in[1];
    const float* bn = (const float*)d_in[2];
    const float* Ws = (const float*)d_in[3];
    const float* Wm = (const float*)d_in[4];
    const float* bL = (const float*)d_in[5];
    const float* we = (const float*)d_in[6];
    const float* be = (const float*)d_in[7];
    const float* Wo = (const float*)d_in[8];
    float* out = (float*)d_out;

    char* w = (char*)d_ws;
    uint32_t*       adj  = (uint32_t*)w;        w += ADJ_BYTES;
    uint32_t*       adjS = (uint32_t*)w;        w += ADJS_BYTES;
    unsigned short* hA   = (unsigned short*)w;  w += HB_BYTES;
    unsigned short* hAT  = (unsigned short*)w;  w += HB_BYTES;
    unsigned short* hB   = (unsigned short*)w;  w += HB_BYTES;
    unsigned short* hBT  = (unsigned short*)w;  w += HB_BYTES;
    unsigned short* WsT  = (unsigned short*)w;  w += WT_BYTES;
    unsigned short* WmT  = (unsigned short*)w;  w += WT_BYTES;

    hipFuncSetAttribute((const void*)layer_kernel,
                        hipFuncAttributeMaxDynamicSharedMemorySize, 131072);

    knn_kernel<<<G_ * ROWT, 256, 0, stream>>>(x, adj);
    sym_kernel<<<G_, 512, 0, stream>>>(adj, adjS);
    wprep_kernel<<<(2 * L_ * D_ * D_) / 256, 256, 0, stream>>>(Ws, Wm, WsT, WmT);
    enc_kernel<<<G_, 256, 0, stream>>>(x, Wn, bn, hA, hAT);

    for (int l = 0; l < L_; ++l) {
        const unsigned short* hi  = (l & 1) ? hB  : hA;
        const unsigned short* hiT = (l & 1) ? hBT : hAT;
        unsigned short* ho  = (l & 1) ? hA  : hB;
        unsigned short* hoT = (l & 1) ? hAT : hBT;
        layer_kernel<<<G_ * 4, 512, 131072, stream>>>(adjS, x, hi, hiT, ho, hoT,
                                                      WsT, WmT, bL, we, be, l);
    }

    pool_kernel<<<G_, 256, 0, stream>>>(hA, Wo, out);
}